// Round 6
// baseline (972.911 us; speedup 1.0000x reference)
//
#include <hip/hip_runtime.h>

// Grouped GEMM (ragged rows over 8 experts) + dequant epilogue.
// R6: faithful m201-style 8-phase 256x256 schedule, BK=64, 8 waves (2Mx4N).
// Per tile: 4 phases x {ds_read, 1 half-tile stage (2 gload/wave), bar,
// lgkm0, setprio, 16 MFMA, setprio, bar}; vmcnt(6) once per tile at p4.

#define BK 64
#define NTILES 32   // 2048/64
#define BM 256
#define BN 256
#define KDIM 2048

typedef __attribute__((ext_vector_type(4))) float f32x4;
typedef __attribute__((ext_vector_type(4))) unsigned int u32x4;
using frag_ab = __attribute__((ext_vector_type(8))) short;
using frag_cd = __attribute__((ext_vector_type(4))) float;

__device__ __forceinline__ unsigned int pack_bf2(float x, float y) {
  unsigned int ux = __float_as_uint(x);
  unsigned int uy = __float_as_uint(y);
  ux += 0x7fffu + ((ux >> 16) & 1u);
  uy += 0x7fffu + ((uy >> 16) & 1u);
  return (ux >> 16) | (uy & 0xffff0000u);
}

__device__ __forceinline__ void gload_lds16(const void* g, void* lds) {
  __builtin_amdgcn_global_load_lds(
      (const __attribute__((address_space(1))) unsigned int*)g,
      (__attribute__((address_space(3))) unsigned int*)lds, 16, 0, 0);
}

// ---------------- convert pass: f32 -> bf16 into ws ----------------
__global__ __launch_bounds__(256)
void convert_kernel(const float* __restrict__ A, const float* __restrict__ B,
                    unsigned short* __restrict__ wa, unsigned short* __restrict__ wb) {
  constexpr long long NA = 16384LL * 2048;
  constexpr long long NB = 8LL * 5632 * 2048;
  constexpr long long NA8 = NA / 8;
  constexpr long long NTOT = (NA + NB) / 8;
  for (long long c = (long long)blockIdx.x * 256 + threadIdx.x; c < NTOT;
       c += (long long)gridDim.x * 256) {
    const float* src;
    unsigned short* dst;
    long long off;
    if (c < NA8) { src = A; dst = wa; off = c * 8; }
    else         { src = B; dst = wb; off = (c - NA8) * 8; }
    f32x4 v0 = *(const f32x4*)(src + off);
    f32x4 v1 = *(const f32x4*)(src + off + 4);
    u32x4 o;
    o[0] = pack_bf2(v0[0], v0[1]);
    o[1] = pack_bf2(v0[2], v0[3]);
    o[2] = pack_bf2(v1[0], v1[1]);
    o[3] = pack_bf2(v1[2], v1[3]);
    *(u32x4*)(dst + off) = o;
  }
}

// ---------------- 8-phase bf16 grouped GEMM ----------------
// LDS: A[2 buf][256r x 64k], B same, bf16, 128 KiB.
// Swizzle: 16B chunk c of row r stored at phys chunk c ^ (r&7); gload dest
// linear, global source pre-permuted; ds_read applies the XOR (rule 21).
__global__ __launch_bounds__(512, 2)
void ggemm_t(const unsigned short* __restrict__ A,
             const unsigned short* __restrict__ B,
             const float* __restrict__ sa,
             const float* __restrict__ sb,
             const int* __restrict__ seg,
             float* __restrict__ C) {
  constexpr int M = 16384, N = 5632, E = 8;
  constexpr int NTC = N / BN;            // 22
  const int nwg = (M / BM) * NTC;        // 1408, % 8 == 0

  int bid = blockIdx.x;
  int sid = (bid & 7) * (nwg >> 3) + (bid >> 3);  // T1
  int mt = sid / NTC, nt = sid % NTC;
  int m0 = mt * BM, n0 = nt * BN;

  int tid = threadIdx.x, lane = tid & 63, w = tid >> 6;
  int l16 = lane & 15, lhi = lane >> 4;
  int wrow = (w >> 2) * 128;   // 2 wave-rows
  int wcol = (w & 3) * 64;     // 4 wave-cols

  __shared__ unsigned short Alds[2][256 * 64];  // 64 KiB
  __shared__ unsigned short Blds[2][256 * 64];  // 64 KiB

  // ds_read swizzled chunk offsets (shorts): chunk (ks*4+lhi) ^ (row&7)
  int c7 = l16 & 7;
  int x0 = ((0 + lhi) ^ c7) * 8;
  int x1 = ((4 + lhi) ^ c7) * 8;
  int offA[8], offB[4];
#pragma unroll
  for (int f = 0; f < 8; ++f) offA[f] = (wrow + f * 16 + l16) * 64;
#pragma unroll
  for (int g = 0; g < 4; ++g) offB[g] = (wcol + g * 16 + l16) * 64;

  // stage source per-lane coords (pre-permuted for the swizzle)
  int srow = lane >> 3;
  int scol = ((lane & 7) ^ srow) * 8;
  const unsigned short* gA = A + (size_t)(m0 + w * 16 + srow) * KDIM + scol;

  frag_ab af[2][8], bf0[2][2], bf1[2][2];

  for (int e = 0; e < E; ++e) {
    int rlo = max(m0, seg[e]);
    int rhi = min(m0 + BM, seg[e + 1]);
    if (rlo >= rhi) continue;
    const unsigned short* gB =
        B + (size_t)e * N * KDIM + (size_t)(n0 + w * 16 + srow) * KDIM + scol;

    frag_cd acc[8][4];
#pragma unroll
    for (int f = 0; f < 8; ++f)
#pragma unroll
      for (int g = 0; g < 4; ++g) acc[f][g] = (frag_cd){0.f, 0.f, 0.f, 0.f};

    // stage half h of tile t into buf b (2 gloads/wave = 16 rows)
    auto stA = [&](int b, int h, int t) {
#pragma unroll
      for (int i = 0; i < 2; ++i)
        gload_lds16(gA + (size_t)(h * 128 + i * 8) * KDIM + t * BK,
                    &Alds[b][(h * 128 + w * 16 + i * 8) * 64]);
    };
    auto stB = [&](int b, int h, int t) {
#pragma unroll
      for (int i = 0; i < 2; ++i)
        gload_lds16(gB + (size_t)(h * 128 + i * 8) * KDIM + t * BK,
                    &Blds[b][(h * 128 + w * 16 + i * 8) * 64]);
    };
    // 16 MFMA: m-frags [f0,f0+4) x n-frags [g0,g0+2) x ks
    auto mfma16 = [&](int f0, int g0, frag_ab (&bf)[2][2]) {
      __builtin_amdgcn_s_setprio(1);
#pragma unroll
      for (int fi = 0; fi < 4; ++fi)
#pragma unroll
        for (int gi = 0; gi < 2; ++gi)
#pragma unroll
          for (int ks = 0; ks < 2; ++ks)
            acc[f0 + fi][g0 + gi] = __builtin_amdgcn_mfma_f32_16x16x32_bf16(
                af[ks][f0 + fi], bf[ks][gi], acc[f0 + fi][g0 + gi], 0, 0, 0);
      __builtin_amdgcn_s_setprio(0);
    };

    // ---- prologue: tile0 all 4 halves, tile1 A0,B0,A1 (14 loads) ----
    stA(0, 0, 0); stB(0, 0, 0); stA(0, 1, 0); stB(0, 1, 0);
    stA(1, 0, 1); stB(1, 0, 1); stA(1, 1, 1);
    asm volatile("s_waitcnt vmcnt(6)" ::: "memory");
    __builtin_amdgcn_s_barrier();

    auto tile = [&](int t, int b) {
      // --- p1: read all A frags + B q0; stage B1(t+1) ---
#pragma unroll
      for (int f = 0; f < 8; ++f) {
        af[0][f] = *(const frag_ab*)(&Alds[b][offA[f] + x0]);
        af[1][f] = *(const frag_ab*)(&Alds[b][offA[f] + x1]);
      }
#pragma unroll
      for (int gi = 0; gi < 2; ++gi) {
        bf0[0][gi] = *(const frag_ab*)(&Blds[b][offB[gi] + x0]);
        bf0[1][gi] = *(const frag_ab*)(&Blds[b][offB[gi] + x1]);
      }
      if (t + 1 < NTILES) stB(b ^ 1, 1, t + 1);
      asm volatile("s_waitcnt lgkmcnt(8)" ::: "memory");
      __builtin_amdgcn_s_barrier();
      asm volatile("s_waitcnt lgkmcnt(0)" ::: "memory");
      mfma16(0, 0, bf0);
      __builtin_amdgcn_s_barrier();
      // --- p2: read B q1; stage A0(t+2) ---
#pragma unroll
      for (int gi = 0; gi < 2; ++gi) {
        bf1[0][gi] = *(const frag_ab*)(&Blds[b][offB[2 + gi] + x0]);
        bf1[1][gi] = *(const frag_ab*)(&Blds[b][offB[2 + gi] + x1]);
      }
      if (t + 2 < NTILES) stA(b, 0, t + 2);
      __builtin_amdgcn_s_barrier();
      asm volatile("s_waitcnt lgkmcnt(0)" ::: "memory");
      mfma16(0, 2, bf1);
      __builtin_amdgcn_s_barrier();
      // --- p3: stage B0(t+2) ---
      if (t + 2 < NTILES) stB(b, 0, t + 2);
      __builtin_amdgcn_s_barrier();
      mfma16(4, 0, bf0);
      __builtin_amdgcn_s_barrier();
      // --- p4: stage A1(t+2); counted vmcnt ---
      if (t + 2 < NTILES) stA(b, 1, t + 2);
      if (t < NTILES - 3) {
        asm volatile("s_waitcnt vmcnt(6)" ::: "memory");
      } else {
        asm volatile("s_waitcnt vmcnt(0)" ::: "memory");
      }
      __builtin_amdgcn_s_barrier();
      mfma16(4, 2, bf1);
      __builtin_amdgcn_s_barrier();
    };

    for (int tt = 0; tt < NTILES; tt += 2) {
      tile(tt, 0);
      tile(tt + 1, 1);
    }

    // ---- epilogue: dequant + masked store ----
    float sbe = sb[e];
#pragma unroll
    for (int f = 0; f < 8; ++f) {
#pragma unroll
      for (int r = 0; r < 4; ++r) {
        int grow = m0 + wrow + f * 16 + lhi * 4 + r;
        if (grow >= rlo && grow < rhi) {
          float s = sa[grow] * sbe;
          float* Crow = C + (size_t)grow * N + n0 + wcol;
#pragma unroll
          for (int g = 0; g < 4; ++g)
            Crow[g * 16 + l16] = acc[f][g][r] * s;
        }
      }
    }
  }
}

extern "C" void kernel_launch(void* const* d_in, const int* in_sizes, int n_in,
                              void* d_out, int out_size, void* d_ws, size_t ws_size,
                              hipStream_t stream) {
  const float* a = (const float*)d_in[0];
  const float* b = (const float*)d_in[1];
  const float* sa = (const float*)d_in[2];
  const float* sb = (const float*)d_in[3];
  const int* seg = (const int*)d_in[4];
  float* out = (float*)d_out;

  constexpr size_t NA = 16384ULL * 2048;
  unsigned short* wa = (unsigned short*)d_ws;
  unsigned short* wb = wa + NA;

  hipLaunchKernelGGL(convert_kernel, dim3(2048), dim3(256), 0, stream, a, b, wa, wb);
  hipLaunchKernelGGL(ggemm_t, dim3((16384 / BM) * (5632 / BN)), dim3(512), 0, stream,
                     wa, wb, sa, sb, seg, out);
}

// Round 7
// 774.045 us; speedup vs baseline: 1.2569x; 1.2569x over previous
//
#include <hip/hip_runtime.h>

// Grouped GEMM (ragged rows over 8 experts) + dequant epilogue.
// R7: convert f32->bf16 into d_ws, then m97-replica GEMM: 128x128 tile,
// BK=32, double-buffered 32 KiB LDS -> 3 blocks/CU (12 waves) so cross-block
// overlap hides the per-step barrier drain (m114/m97 mechanism).

#define BK 32
#define NKSTEP 64   // 2048/32
#define KDIM 2048

typedef __attribute__((ext_vector_type(4))) float f32x4;
typedef __attribute__((ext_vector_type(4))) unsigned int u32x4;
using frag_ab = __attribute__((ext_vector_type(8))) short;
using frag_cd = __attribute__((ext_vector_type(4))) float;

__device__ __forceinline__ unsigned int pack_bf2(float x, float y) {
  unsigned int ux = __float_as_uint(x);
  unsigned int uy = __float_as_uint(y);
  ux += 0x7fffu + ((ux >> 16) & 1u);
  uy += 0x7fffu + ((uy >> 16) & 1u);
  return (ux >> 16) | (uy & 0xffff0000u);
}

__device__ __forceinline__ void gload_lds16(const void* g, void* lds) {
  __builtin_amdgcn_global_load_lds(
      (const __attribute__((address_space(1))) unsigned int*)g,
      (__attribute__((address_space(3))) unsigned int*)lds, 16, 0, 0);
}

// ---------------- convert pass: f32 -> bf16 into ws ----------------
__global__ __launch_bounds__(256)
void convert_kernel(const float* __restrict__ A, const float* __restrict__ B,
                    unsigned short* __restrict__ wa, unsigned short* __restrict__ wb) {
  constexpr long long NA = 16384LL * 2048;
  constexpr long long NB = 8LL * 5632 * 2048;
  constexpr long long NA8 = NA / 8;
  constexpr long long NTOT = (NA + NB) / 8;
  for (long long c = (long long)blockIdx.x * 256 + threadIdx.x; c < NTOT;
       c += (long long)gridDim.x * 256) {
    const float* src;
    unsigned short* dst;
    long long off;
    if (c < NA8) { src = A; dst = wa; off = c * 8; }
    else         { src = B; dst = wb; off = (c - NA8) * 8; }
    f32x4 v0 = *(const f32x4*)(src + off);
    f32x4 v1 = *(const f32x4*)(src + off + 4);
    u32x4 o;
    o[0] = pack_bf2(v0[0], v0[1]);
    o[1] = pack_bf2(v0[2], v0[3]);
    o[2] = pack_bf2(v1[0], v1[1]);
    o[3] = pack_bf2(v1[2], v1[3]);
    *(u32x4*)(dst + off) = o;
  }
}

// ---------------- bf16 grouped GEMM, 3 blocks/CU ----------------
// LDS per op per buf: [128 rows][32 k] bf16 = 8 KiB; total 32 KiB.
// Swizzle (both-sides, rule 21): 16B chunk c of row r at phys chunk c^(r&3);
// gload dest linear, global source pre-permuted; ds_read applies the XOR.
__global__ __launch_bounds__(256, 3)
void ggemm_o(const unsigned short* __restrict__ A,
             const unsigned short* __restrict__ B,
             const float* __restrict__ sa,
             const float* __restrict__ sb,
             const int* __restrict__ seg,
             float* __restrict__ C) {
  constexpr int M = 16384, N = 5632, E = 8;
  constexpr int NTC = N / 128;          // 44
  const int nwg = (M / 128) * NTC;      // 5632, % 8 == 0

  int bid = blockIdx.x;
  int sid = (bid & 7) * (nwg >> 3) + (bid >> 3);  // T1 XCD swizzle
  int mt = sid / NTC, nt = sid % NTC;
  int m0 = mt * 128, n0 = nt * 128;

  int tid = threadIdx.x, lane = tid & 63, w = tid >> 6;
  int wr = (w >> 1) * 64, wc = (w & 1) * 64;   // 2x2 wave grid
  int l16 = lane & 15, lhi = lane >> 4;

  __shared__ unsigned short Asm[2][128 * 32];  // 16 KiB
  __shared__ unsigned short Bsm[2][128 * 32];  // 16 KiB

  // stage: per gload, 16 rows x 64B; lane -> (row=lane>>2, phys chunk=lane&3);
  // fetch logical chunk (lane&3)^(row&3) so ds_read's XOR sees linear data.
  int sr = lane >> 2;
  int scol = (((lane & 3) ^ (sr & 3)) * 8);
  const unsigned short* gA = A + (size_t)(m0 + w * 32 + sr) * KDIM + scol;

  // ds_read swizzled offsets (shorts): row*32 + (lhi ^ (row&3))*8
  int xA[4], xB[4];
#pragma unroll
  for (int i = 0; i < 4; ++i)
    xA[i] = (wr + i * 16 + l16) * 32 + ((lhi ^ (l16 & 3)) * 8);
#pragma unroll
  for (int j = 0; j < 4; ++j)
    xB[j] = (wc + j * 16 + l16) * 32 + ((lhi ^ (l16 & 3)) * 8);

  for (int e = 0; e < E; ++e) {
    int rlo = max(m0, seg[e]);
    int rhi = min(m0 + 128, seg[e + 1]);
    if (rlo >= rhi) continue;
    const unsigned short* gB =
        B + (size_t)e * N * KDIM + (size_t)(n0 + w * 32 + sr) * KDIM + scol;

    frag_cd acc[4][4];
#pragma unroll
    for (int i = 0; i < 4; ++i)
#pragma unroll
      for (int j = 0; j < 4; ++j) acc[i][j] = (frag_cd){0.f, 0.f, 0.f, 0.f};

    auto stage = [&](int b, int kt) {
#pragma unroll
      for (int i = 0; i < 2; ++i) {
        gload_lds16(gA + (size_t)i * 16 * KDIM + kt * BK,
                    &Asm[b][(w * 32 + i * 16) * 32]);
        gload_lds16(gB + (size_t)i * 16 * KDIM + kt * BK,
                    &Bsm[b][(w * 32 + i * 16) * 32]);
      }
    };
    auto compute = [&](int b) {
      frag_ab af[4], bf[4];
#pragma unroll
      for (int i = 0; i < 4; ++i) af[i] = *(const frag_ab*)(&Asm[b][xA[i]]);
#pragma unroll
      for (int j = 0; j < 4; ++j) bf[j] = *(const frag_ab*)(&Bsm[b][xB[j]]);
#pragma unroll
      for (int i = 0; i < 4; ++i)
#pragma unroll
        for (int j = 0; j < 4; ++j)
          acc[i][j] = __builtin_amdgcn_mfma_f32_16x16x32_bf16(
              af[i], bf[j], acc[i][j], 0, 0, 0);
    };

    stage(0, 0);
    __syncthreads();
    for (int kt = 0; kt < NKSTEP; ++kt) {
      if (kt + 1 < NKSTEP) stage((kt + 1) & 1, kt + 1);  // issue-early
      compute(kt & 1);
      __syncthreads();
    }

    float sbe = sb[e];
#pragma unroll
    for (int i = 0; i < 4; ++i) {
#pragma unroll
      for (int r = 0; r < 4; ++r) {
        int grow = m0 + wr + i * 16 + lhi * 4 + r;
        if (grow >= rlo && grow < rhi) {
          float s = sa[grow] * sbe;
          float* Crow = C + (size_t)grow * N + n0 + wc;
#pragma unroll
          for (int j = 0; j < 4; ++j)
            Crow[j * 16 + l16] = acc[i][j][r] * s;
        }
      }
    }
  }
}

extern "C" void kernel_launch(void* const* d_in, const int* in_sizes, int n_in,
                              void* d_out, int out_size, void* d_ws, size_t ws_size,
                              hipStream_t stream) {
  const float* a = (const float*)d_in[0];
  const float* b = (const float*)d_in[1];
  const float* sa = (const float*)d_in[2];
  const float* sb = (const float*)d_in[3];
  const int* seg = (const int*)d_in[4];
  float* out = (float*)d_out;

  constexpr size_t NA = 16384ULL * 2048;
  unsigned short* wa = (unsigned short*)d_ws;
  unsigned short* wb = wa + NA;

  hipLaunchKernelGGL(convert_kernel, dim3(2048), dim3(256), 0, stream, a, b, wa, wb);
  hipLaunchKernelGGL(ggemm_o, dim3(5632), dim3(256), 0, stream,
                     wa, wb, sa, sb, seg, out);
}